// Round 2
// baseline (1557.481 us; speedup 1.0000x reference)
//
#include <hip/hip_runtime.h>
#include <hip/hip_bf16.h>

#define T_TOK 1024
#define H_DIM 2048
#define E_NUM 32
#define I_DIM 768
#define N2I   1536
#define SK    36   // LDS row stride in shorts (BK=32 + 4 pad)

typedef __attribute__((ext_vector_type(8))) __bf16 bf16x8;
typedef __attribute__((ext_vector_type(4))) float  f32x4;

__device__ __forceinline__ short f2bf(float f) {
  union { float f; unsigned u; } a; a.f = f;
  unsigned u = a.u;
  u += 0x7FFFu + ((u >> 16) & 1u);   // RNE to bf16
  return (short)(u >> 16);
}

// single-instruction packed f32->bf16 (RNE), lo -> D[15:0], hi -> D[31:16]
__device__ __forceinline__ unsigned pkbf(float lo, float hi) {
  unsigned r;
  asm("v_cvt_pk_bf16_f32 %0, %1, %2" : "=v"(r) : "v"(lo), "v"(hi));
  return r;
}

union FR { uint2 d[2]; bf16x8 v; };

// ---------------- routing ----------------
__global__ void zero_cnt_kernel(int* cnt) {
  if (threadIdx.x < E_NUM) cnt[threadIdx.x] = 0;
}

__global__ void route_kernel(const float* __restrict__ X, const float* __restrict__ GW,
                             const float* __restrict__ gbias,
                             int* __restrict__ cnt, int* __restrict__ toks,
                             float* __restrict__ tokw, int* __restrict__ slots) {
  const int t = blockIdx.x;
  const int tid = threadIdx.x;
  __shared__ float xs[H_DIM];
  const float4* xg = (const float4*)(X + (long)t * H_DIM);
  float4* xl = (float4*)xs;
  for (int i = tid; i < H_DIM / 4; i += 256) xl[i] = xg[i];
  __syncthreads();
  const int e = tid >> 3, l = tid & 7;
  const float* w = GW + (long)e * H_DIM;
  float p = 0.f;
  for (int h = l; h < H_DIM; h += 8) p += xs[h] * w[h];
  p += __shfl_xor(p, 4);
  p += __shfl_xor(p, 2);
  p += __shfl_xor(p, 1);
  __shared__ float lg[E_NUM];
  if (l == 0) lg[e] = p;
  __syncthreads();
  if (tid == 0) {
    float su[E_NUM], sc[E_NUM];
    for (int i = 0; i < E_NUM; ++i) {
      float s = 1.f / (1.f + __expf(-lg[i]));
      su[i] = s; sc[i] = s + gbias[i];
    }
    float gs[4];
    for (int g = 0; g < 4; ++g) {
      float m1 = -1e30f, m2 = -1e30f;
      for (int j = 0; j < 8; ++j) {
        float v = sc[g * 8 + j];
        if (v > m1) { m2 = m1; m1 = v; } else if (v > m2) m2 = v;
      }
      gs[g] = m1 + m2;
    }
    int g1 = 0;
    for (int g = 1; g < 4; ++g) if (gs[g] > gs[g1]) g1 = g;
    int g2 = -1;
    for (int g = 0; g < 4; ++g) { if (g == g1) continue; if (g2 < 0 || gs[g] > gs[g2]) g2 = g; }
    bool mask[E_NUM], taken[E_NUM];
    for (int i = 0; i < E_NUM; ++i) {
      int g = i >> 3;
      mask[i] = (g == g1) || (g == g2);
      taken[i] = false;
    }
    int ids[8]; float wsum = 0.f;
    for (int k = 0; k < 8; ++k) {
      int best = -1;
      for (int i = 0; i < E_NUM; ++i) {
        if (!mask[i] || taken[i]) continue;
        if (best < 0 || sc[i] > sc[best]) best = i;
      }
      taken[best] = true; ids[k] = best; wsum += su[best];
    }
    float inv = 2.5f / wsum;
    for (int k = 0; k < 8; ++k) {
      int ei = ids[k];
      int pos = atomicAdd(&cnt[ei], 1);
      toks[ei * T_TOK + pos] = t;
      tokw[ei * T_TOK + pos] = su[ei] * inv;
      slots[t * 8 + k] = (ei << 10) | pos;
    }
  }
}

__global__ void offs_kernel(const int* __restrict__ cnt, int* __restrict__ offs) {
  if (threadIdx.x == 0) {
    int run = 0;
    for (int e = 0; e < E_NUM; ++e) { offs[e] = run; run += cnt[e]; }
    offs[E_NUM] = run;
  }
}

// ---------------- X -> bf16 ----------------
__global__ void xconv_kernel(const float* __restrict__ X, unsigned short* __restrict__ Xb) {
  int i = (blockIdx.x * 256 + threadIdx.x) * 4;
  float4 v = *(const float4*)(X + i);
  uint2 o;
  o.x = pkbf(v.x, v.y);
  o.y = pkbf(v.z, v.w);
  *(uint2*)(Xb + i) = o;
}

// ======== fused gate_up + SiLU GEMM (merged shared expert as z==E_NUM) ========
// BM=128, BN=64 (x2 halves), BK=32, 4 waves. Depth-3 register prefetch,
// single LDS buffer, raw s_barrier (no vmcnt drain) + counted compiler waits.

#define GU_DECL(S) uint4 pa0##S, pa1##S; float4 pw00##S, pw01##S, pw10##S, pw11##S;

#define GU_LOAD(S, K0) { \
  const int kc_ = (K0) <= (H_DIM - 32) ? (K0) : (H_DIM - 32); \
  const uint4* p_ = (const uint4*)(xp + kc_); \
  pa0##S = p_[0]; pa1##S = p_[1]; \
  const long kr0_ = (long)(kc_ + kk2 * 2) * N2I; \
  const long kr1_ = (long)(kc_ + 16 + kk2 * 2) * N2I; \
  pw00##S = *(const float4*)(wp0 + kr0_); \
  pw01##S = *(const float4*)(wp0 + kr0_ + N2I); \
  pw10##S = *(const float4*)(wp0 + kr1_); \
  pw11##S = *(const float4*)(wp0 + kr1_ + N2I); \
}

#define GU_STORE(S) { \
  *(uint2*)&As[abase +  0] = make_uint2(pa0##S.x, pa0##S.y); \
  *(uint2*)&As[abase +  4] = make_uint2(pa0##S.z, pa0##S.w); \
  *(uint2*)&As[abase +  8] = make_uint2(pa1##S.x, pa1##S.y); \
  *(uint2*)&As[abase + 12] = make_uint2(pa1##S.z, pa1##S.w); \
  short* bs_ = &Bs[hh][0]; \
  { const int bb_ = kk2 * 2; \
    *(unsigned*)&bs_[(fm4 + 0) * SK + bb_] = pkbf(pw00##S.x, pw01##S.x); \
    *(unsigned*)&bs_[(fm4 + 1) * SK + bb_] = pkbf(pw00##S.y, pw01##S.y); \
    *(unsigned*)&bs_[(fm4 + 2) * SK + bb_] = pkbf(pw00##S.z, pw01##S.z); \
    *(unsigned*)&bs_[(fm4 + 3) * SK + bb_] = pkbf(pw00##S.w, pw01##S.w); } \
  { const int bb_ = 16 + kk2 * 2; \
    *(unsigned*)&bs_[(fm4 + 0) * SK + bb_] = pkbf(pw10##S.x, pw11##S.x); \
    *(unsigned*)&bs_[(fm4 + 1) * SK + bb_] = pkbf(pw10##S.y, pw11##S.y); \
    *(unsigned*)&bs_[(fm4 + 2) * SK + bb_] = pkbf(pw10##S.z, pw11##S.z); \
    *(unsigned*)&bs_[(fm4 + 3) * SK + bb_] = pkbf(pw10##S.w, pw11##S.w); } \
}

#define GU_COMPUTE() { \
  bf16x8 af[4]; \
  _Pragma("unroll") \
  for (int mi = 0; mi < 4; ++mi) { \
    FR f; \
    const int ra = (wm + mi * 16 + fm) * SK + fq * 8; \
    f.d[0] = *(const uint2*)&As[ra]; \
    f.d[1] = *(const uint2*)&As[ra + 4]; \
    af[mi] = f.v; \
  } \
  bf16x8 bfr[2][2]; \
  _Pragma("unroll") \
  for (int h = 0; h < 2; ++h) \
    _Pragma("unroll") \
    for (int ni = 0; ni < 2; ++ni) { \
      FR f; \
      const int rb = (wn + ni * 16 + fm) * SK + fq * 8; \
      f.d[0] = *(const uint2*)&Bs[h][rb]; \
      f.d[1] = *(const uint2*)&Bs[h][rb + 4]; \
      bfr[h][ni] = f.v; \
    } \
  _Pragma("unroll") \
  for (int mi = 0; mi < 4; ++mi) \
    _Pragma("unroll") \
    for (int ni = 0; ni < 2; ++ni) { \
      accg[mi][ni] = __builtin_amdgcn_mfma_f32_16x16x32_bf16(af[mi], bfr[0][ni], accg[mi][ni], 0, 0, 0); \
      accu[mi][ni] = __builtin_amdgcn_mfma_f32_16x16x32_bf16(af[mi], bfr[1][ni], accu[mi][ni], 0, 0, 0); \
    } \
}

#define GU_ITER(S, IT) { \
  GU_COMPUTE(); \
  __builtin_amdgcn_sched_barrier(0); \
  __builtin_amdgcn_s_barrier(); \
  __builtin_amdgcn_sched_barrier(0); \
  GU_STORE(S); \
  GU_LOAD(S, ((IT) + 4) * 32); \
  asm volatile("s_waitcnt lgkmcnt(0)" ::: "memory"); \
  __builtin_amdgcn_sched_barrier(0); \
  __builtin_amdgcn_s_barrier(); \
}

__global__ __launch_bounds__(256, 3)
void gateup_kernel(const unsigned short* __restrict__ Xb,
                   const float* __restrict__ Wr, const float* __restrict__ Ws,
                   const int* __restrict__ cnt, const int* __restrict__ offs,
                   const int* __restrict__ toks,
                   unsigned short* __restrict__ act_r, unsigned short* __restrict__ act_s) {
  const int mt = blockIdx.x, nb = blockIdx.y, e = blockIdx.z;
  const bool SHARED = (e == E_NUM);
  const int count = SHARED ? T_TOK : cnt[e];
  if (mt * 128 >= count) return;
  const int rowbase = SHARED ? 0 : offs[e];
  const int* tl = SHARED ? nullptr : (toks + e * T_TOK);
  const float* Wb = SHARED ? Ws : (Wr + (long)e * H_DIM * N2I);
  unsigned short* act = SHARED ? act_s : act_r;
  const int m0 = mt * 128, n0 = nb * 64;
  __shared__ short As[128 * SK];
  __shared__ short Bs[2][64 * SK];
  const int tid = threadIdx.x;
  const int arow = tid >> 1, ahalf = tid & 1;
  const int ar = min(m0 + arow, count - 1);
  const long agrow = SHARED ? (long)ar : (long)tl[ar];
  const unsigned short* xp = Xb + agrow * H_DIM + ahalf * 16;
  const int abase = arow * SK + ahalf * 16;
  const int fm4 = (tid & 15) * 4;
  const int kk2 = (tid >> 4) & 7;
  const int hh  = tid >> 7;
  const float* wp0 = Wb + hh * I_DIM + n0 + fm4;
  const int lane = tid & 63, wv = tid >> 6;
  const int wm = (wv >> 1) * 64, wn = (wv & 1) * 32;
  const int fm = lane & 15, fq = lane >> 4;
  f32x4 accg[4][2] = {};
  f32x4 accu[4][2] = {};

  GU_DECL(0) GU_DECL(1) GU_DECL(2)
  // prologue: tiles 0,1,2 into sets 0,1,2; stage tile 0; refill set0 with tile 3
  GU_LOAD(0, 0)
  GU_LOAD(1, 32)
  GU_LOAD(2, 64)
  GU_STORE(0)
  GU_LOAD(0, 96)
  asm volatile("s_waitcnt lgkmcnt(0)" ::: "memory");
  __builtin_amdgcn_sched_barrier(0);
  __builtin_amdgcn_s_barrier();

  const int NT = H_DIM / 32;  // 64
  for (int it = 0; it < NT; it += 3) {
    GU_ITER(1, it);
    if (it + 1 < NT) GU_ITER(2, it + 1);
    if (it + 2 < NT) GU_ITER(0, it + 2);
  }

  // ---- epilogue: act = silu(g) * u, bf16 store ----
  #pragma unroll
  for (int mi = 0; mi < 4; ++mi)
    #pragma unroll
    for (int ni = 0; ni < 2; ++ni)
      #pragma unroll
      for (int r = 0; r < 4; ++r) {
        int lr = wm + mi * 16 + fq * 4 + r;
        int gr = m0 + lr;
        if (gr < count) {
          int lc = wn + ni * 16 + fm;
          float g = accg[mi][ni][r], u = accu[mi][ni][r];
          float a = g / (1.f + __expf(-g)) * u;
          act[(long)(rowbase + gr) * I_DIM + n0 + lc] = (unsigned short)f2bf(a);
        }
      }
}

// ======== down GEMM (merged shared expert as z==E_NUM) ========
#define DN_DECL(S) uint4 qa0##S, qa1##S; float4 qw0##S, qw1##S;

#define DN_LOAD(S, K0) { \
  const int kc_ = (K0) <= (I_DIM - 32) ? (K0) : (I_DIM - 32); \
  const uint4* p_ = (const uint4*)(ap + kc_); \
  qa0##S = p_[0]; qa1##S = p_[1]; \
  const long kr_ = (long)(kc_ + kk2 * 2) * H_DIM; \
  qw0##S = *(const float4*)(wp0 + kr_); \
  qw1##S = *(const float4*)(wp0 + kr_ + H_DIM); \
}

#define DN_STORE(S) { \
  *(uint2*)&As[abase +  0] = make_uint2(qa0##S.x, qa0##S.y); \
  *(uint2*)&As[abase +  4] = make_uint2(qa0##S.z, qa0##S.w); \
  *(uint2*)&As[abase +  8] = make_uint2(qa1##S.x, qa1##S.y); \
  *(uint2*)&As[abase + 12] = make_uint2(qa1##S.z, qa1##S.w); \
  const int bb_ = kk2 * 2; \
  *(unsigned*)&Bs[(fm4 + 0) * SK + bb_] = pkbf(qw0##S.x, qw1##S.x); \
  *(unsigned*)&Bs[(fm4 + 1) * SK + bb_] = pkbf(qw0##S.y, qw1##S.y); \
  *(unsigned*)&Bs[(fm4 + 2) * SK + bb_] = pkbf(qw0##S.z, qw1##S.z); \
  *(unsigned*)&Bs[(fm4 + 3) * SK + bb_] = pkbf(qw0##S.w, qw1##S.w); \
}

#define DN_COMPUTE() { \
  bf16x8 af[4]; \
  _Pragma("unroll") \
  for (int mi = 0; mi < 4; ++mi) { \
    FR f; \
    const int ra = (wm + mi * 16 + fm) * SK + fq * 8; \
    f.d[0] = *(const uint2*)&As[ra]; \
    f.d[1] = *(const uint2*)&As[ra + 4]; \
    af[mi] = f.v; \
  } \
  bf16x8 bfr[2]; \
  _Pragma("unroll") \
  for (int ni = 0; ni < 2; ++ni) { \
    FR f; \
    const int rb = (wn + ni * 16 + fm) * SK + fq * 8; \
    f.d[0] = *(const uint2*)&Bs[rb]; \
    f.d[1] = *(const uint2*)&Bs[rb + 4]; \
    bfr[ni] = f.v; \
  } \
  _Pragma("unroll") \
  for (int mi = 0; mi < 4; ++mi) \
    _Pragma("unroll") \
    for (int ni = 0; ni < 2; ++ni) \
      acc[mi][ni] = __builtin_amdgcn_mfma_f32_16x16x32_bf16(af[mi], bfr[ni], acc[mi][ni], 0, 0, 0); \
}

#define DN_ITER(S, IT) { \
  DN_COMPUTE(); \
  __builtin_amdgcn_sched_barrier(0); \
  __builtin_amdgcn_s_barrier(); \
  __builtin_amdgcn_sched_barrier(0); \
  DN_STORE(S); \
  DN_LOAD(S, ((IT) + 4) * 32); \
  asm volatile("s_waitcnt lgkmcnt(0)" ::: "memory"); \
  __builtin_amdgcn_sched_barrier(0); \
  __builtin_amdgcn_s_barrier(); \
}

__global__ __launch_bounds__(256, 3)
void down_kernel(const unsigned short* __restrict__ act_r, const unsigned short* __restrict__ act_s,
                 const float* __restrict__ Wr, const float* __restrict__ Ws,
                 const int* __restrict__ cnt, const int* __restrict__ offs,
                 const int* __restrict__ toks, const float* __restrict__ tokw,
                 float* __restrict__ eout, float* __restrict__ sout,
                 float* __restrict__ out) {
  const int mt = blockIdx.x, nb = blockIdx.y, e = blockIdx.z;
  const bool SHARED = (e == E_NUM);
  const int count = SHARED ? T_TOK : cnt[e];
  if (mt * 128 >= count) return;
  const int rowbase = SHARED ? 0 : offs[e];
  const unsigned short* ab = SHARED ? act_s : act_r;
  const float* Wb = SHARED ? Ws : (Wr + (long)e * I_DIM * H_DIM);
  const int m0 = mt * 128, n0 = nb * 64;
  __shared__ short As[128 * SK];
  __shared__ short Bs[64 * SK];
  const int tid = threadIdx.x;
  const int arow = tid >> 1, ahalf = tid & 1;
  const int ar = min(m0 + arow, count - 1);
  const unsigned short* ap = ab + (long)(rowbase + ar) * I_DIM + ahalf * 16;
  const int abase = arow * SK + ahalf * 16;
  const int fm4 = (tid & 15) * 4;
  const int kk2 = tid >> 4;           // 0..15 -> BK=32 as k-pairs
  const float* wp0 = Wb + n0 + fm4;
  const int lane = tid & 63, wv = tid >> 6;
  const int wm = (wv >> 1) * 64, wn = (wv & 1) * 32;
  const int fm = lane & 15, fq = lane >> 4;
  f32x4 acc[4][2] = {};

  DN_DECL(0) DN_DECL(1) DN_DECL(2)
  DN_LOAD(0, 0)
  DN_LOAD(1, 32)
  DN_LOAD(2, 64)
  DN_STORE(0)
  DN_LOAD(0, 96)
  asm volatile("s_waitcnt lgkmcnt(0)" ::: "memory");
  __builtin_amdgcn_sched_barrier(0);
  __builtin_amdgcn_s_barrier();

  const int NT = I_DIM / 32;  // 24
  for (int it = 0; it < NT; it += 3) {
    DN_ITER(1, it);
    if (it + 1 < NT) DN_ITER(2, it + 1);
    if (it + 2 < NT) DN_ITER(0, it + 2);
  }

  #pragma unroll
  for (int mi = 0; mi < 4; ++mi)
    #pragma unroll
    for (int ni = 0; ni < 2; ++ni)
      #pragma unroll
      for (int r = 0; r < 4; ++r) {
        int lr = wm + mi * 16 + fq * 4 + r;
        int gr = m0 + lr;
        if (gr < count) {
          int lc = wn + ni * 16 + fm;
          float v = acc[mi][ni][r];
          if (eout) {
            if (SHARED) {
              sout[(long)gr * H_DIM + n0 + lc] = v;
            } else {
              float wgt = tokw[e * T_TOK + gr];
              eout[(long)(rowbase + gr) * H_DIM + n0 + lc] = v * wgt;
            }
          } else {
            if (SHARED) {
              atomicAdd(&out[(long)gr * H_DIM + n0 + lc], v);
            } else {
              float wgt = tokw[e * T_TOK + gr];
              int t = toks[e * T_TOK + gr];
              atomicAdd(&out[(long)t * H_DIM + n0 + lc], v * wgt);
            }
          }
        }
      }
}

// ---------------- combine: out[t] = sout[t] + sum_k eout[slot(t,k)] ----------------
__global__ __launch_bounds__(256)
void combine_kernel(const float* __restrict__ eout, const float* __restrict__ sout,
                    const int* __restrict__ offs, const int* __restrict__ slots,
                    float* __restrict__ out) {
  const int b = blockIdx.x;
  const int t = b >> 1, half = b & 1;
  const int h = half * 1024 + threadIdx.x * 4;
  float4 acc = *(const float4*)(sout + (long)t * H_DIM + h);
  #pragma unroll
  for (int k = 0; k < 8; ++k) {
    int s = slots[t * 8 + k];
    int ei = s >> 10, pos = s & 1023;
    long row = (long)offs[ei] + pos;
    float4 v = *(const float4*)(eout + row * H_DIM + h);
    acc.x += v.x; acc.y += v.y; acc.z += v.z; acc.w += v.w;
  }
  *(float4*)(out + (long)t * H_DIM + h) = acc;
}

// ---------------- launch ----------------
extern "C" void kernel_launch(void* const* d_in, const int* in_sizes, int n_in,
                              void* d_out, int out_size, void* d_ws, size_t ws_size,
                              hipStream_t stream) {
  const float* X   = (const float*)d_in[0];
  const float* GW  = (const float*)d_in[1];
  const float* GB  = (const float*)d_in[2];
  const float* WGU = (const float*)d_in[3];
  const float* WD  = (const float*)d_in[4];
  const float* SGU = (const float*)d_in[5];
  const float* SD  = (const float*)d_in[6];
  float* out = (float*)d_out;
  char* ws = (char*)d_ws;

  int*   cnt   = (int*)(ws + 0);
  int*   offs  = (int*)(ws + 512);
  int*   slots = (int*)(ws + 4096);                         // 32 KB
  int*   toks  = (int*)(ws + 65536);                        // 128 KB
  float* tokw  = (float*)(ws + 196608);                     // 128 KB
  unsigned short* Xb    = (unsigned short*)(ws + 327680);   // 4 MB
  unsigned short* act_s = (unsigned short*)(ws + 4521984);  // 1.5 MB
  unsigned short* act_r = (unsigned short*)(ws + 6094848);  // 12.58 MB
  float* sout = (float*)(ws + 18677760);                    // 8.39 MB
  const size_t EOUT_OFF = 27066368;
  const size_t need = EOUT_OFF + (size_t)8192 * H_DIM * sizeof(float);  // 94.2 MB total
  float* eout = (ws_size >= need) ? (float*)(ws + EOUT_OFF) : nullptr;

  zero_cnt_kernel<<<1, 64, 0, stream>>>(cnt);
  route_kernel<<<T_TOK, 256, 0, stream>>>(X, GW, GB, cnt, toks, tokw, slots);
  offs_kernel<<<1, 64, 0, stream>>>(cnt, offs);
  xconv_kernel<<<T_TOK * H_DIM / 1024, 256, 0, stream>>>(X, Xb);
  // merged shared (z == E_NUM) + routed experts
  gateup_kernel<<<dim3(8, 12, E_NUM + 1), 256, 0, stream>>>(Xb, WGU, SGU, cnt, offs, toks, act_r, act_s);
  if (!eout) hipMemsetAsync(out, 0, (size_t)T_TOK * H_DIM * sizeof(float), stream);
  down_kernel<<<dim3(8, 32, E_NUM + 1), 256, 0, stream>>>(act_r, act_s, WD, SD, cnt, offs, toks, tokw,
                                                          eout, sout, out);
  if (eout) combine_kernel<<<T_TOK * 2, 256, 0, stream>>>(eout, sout, offs, slots, out);
}

// Round 3
// 1552.479 us; speedup vs baseline: 1.0032x; 1.0032x over previous
//
#include <hip/hip_runtime.h>
#include <hip/hip_bf16.h>

#define T_TOK 1024
#define H_DIM 2048
#define E_NUM 32
#define I_DIM 768
#define N2I   1536
#define BK    64
#define SKB   72   // LDS row stride in shorts (BK=64 + 8 pad; 144B rows, 16B-aligned)

typedef __attribute__((ext_vector_type(8))) __bf16 bf16x8;
typedef __attribute__((ext_vector_type(4))) float  f32x4;

__device__ __forceinline__ short f2bf(float f) {
  union { float f; unsigned u; } a; a.f = f;
  unsigned u = a.u;
  u += 0x7FFFu + ((u >> 16) & 1u);   // RNE to bf16
  return (short)(u >> 16);
}

// single-instruction packed f32->bf16 (RNE), lo -> D[15:0], hi -> D[31:16]
__device__ __forceinline__ unsigned pkbf(float lo, float hi) {
  unsigned r;
  asm("v_cvt_pk_bf16_f32 %0, %1, %2" : "=v"(r) : "v"(lo), "v"(hi));
  return r;
}

union FR { uint2 d[2]; bf16x8 v; };

// ---------------- routing ----------------
__global__ void zero_cnt_kernel(int* cnt) {
  if (threadIdx.x < E_NUM) cnt[threadIdx.x] = 0;
}

__global__ void route_kernel(const float* __restrict__ X, const float* __restrict__ GW,
                             const float* __restrict__ gbias,
                             int* __restrict__ cnt, int* __restrict__ toks,
                             float* __restrict__ tokw, int* __restrict__ slots) {
  const int t = blockIdx.x;
  const int tid = threadIdx.x;
  __shared__ float xs[H_DIM];
  const float4* xg = (const float4*)(X + (long)t * H_DIM);
  float4* xl = (float4*)xs;
  for (int i = tid; i < H_DIM / 4; i += 256) xl[i] = xg[i];
  __syncthreads();
  const int e = tid >> 3, l = tid & 7;
  const float* w = GW + (long)e * H_DIM;
  float p = 0.f;
  for (int h = l; h < H_DIM; h += 8) p += xs[h] * w[h];
  p += __shfl_xor(p, 4);
  p += __shfl_xor(p, 2);
  p += __shfl_xor(p, 1);
  __shared__ float lg[E_NUM];
  if (l == 0) lg[e] = p;
  __syncthreads();
  if (tid == 0) {
    float su[E_NUM], sc[E_NUM];
    for (int i = 0; i < E_NUM; ++i) {
      float s = 1.f / (1.f + __expf(-lg[i]));
      su[i] = s; sc[i] = s + gbias[i];
    }
    float gs[4];
    for (int g = 0; g < 4; ++g) {
      float m1 = -1e30f, m2 = -1e30f;
      for (int j = 0; j < 8; ++j) {
        float v = sc[g * 8 + j];
        if (v > m1) { m2 = m1; m1 = v; } else if (v > m2) m2 = v;
      }
      gs[g] = m1 + m2;
    }
    int g1 = 0;
    for (int g = 1; g < 4; ++g) if (gs[g] > gs[g1]) g1 = g;
    int g2 = -1;
    for (int g = 0; g < 4; ++g) { if (g == g1) continue; if (g2 < 0 || gs[g] > gs[g2]) g2 = g; }
    bool mask[E_NUM], taken[E_NUM];
    for (int i = 0; i < E_NUM; ++i) {
      int g = i >> 3;
      mask[i] = (g == g1) || (g == g2);
      taken[i] = false;
    }
    int ids[8]; float wsum = 0.f;
    for (int k = 0; k < 8; ++k) {
      int best = -1;
      for (int i = 0; i < E_NUM; ++i) {
        if (!mask[i] || taken[i]) continue;
        if (best < 0 || sc[i] > sc[best]) best = i;
      }
      taken[best] = true; ids[k] = best; wsum += su[best];
    }
    float inv = 2.5f / wsum;
    for (int k = 0; k < 8; ++k) {
      int ei = ids[k];
      int pos = atomicAdd(&cnt[ei], 1);
      toks[ei * T_TOK + pos] = t;
      tokw[ei * T_TOK + pos] = su[ei] * inv;
      slots[t * 8 + k] = (ei << 10) | pos;
    }
  }
}

__global__ void offs_kernel(const int* __restrict__ cnt, int* __restrict__ offs) {
  if (threadIdx.x == 0) {
    int run = 0;
    for (int e = 0; e < E_NUM; ++e) { offs[e] = run; run += cnt[e]; }
    offs[E_NUM] = run;
  }
}

// ---------------- X -> bf16 ----------------
__global__ void xconv_kernel(const float* __restrict__ X, unsigned short* __restrict__ Xb) {
  int i = (blockIdx.x * 256 + threadIdx.x) * 4;
  float4 v = *(const float4*)(X + i);
  uint2 o;
  o.x = pkbf(v.x, v.y);
  o.y = pkbf(v.z, v.w);
  *(uint2*)(Xb + i) = o;
}

// ======== fused gate_up + SiLU GEMM (merged shared expert as z==E_NUM) ========
// BM=64, BN=64 (x2 halves), BK=64, 4 waves (2x2). Single LDS buffer, plain
// syncthreads, loads issued at step top; TLP (many blocks/CU) hides latency.
__global__ __launch_bounds__(256, 4)
void gateup_kernel(const unsigned short* __restrict__ Xb,
                   const float* __restrict__ Wr, const float* __restrict__ Ws,
                   const int* __restrict__ cnt, const int* __restrict__ offs,
                   const int* __restrict__ toks,
                   unsigned short* __restrict__ act_r, unsigned short* __restrict__ act_s) {
  const int mt = blockIdx.x, nb = blockIdx.y, e = blockIdx.z;
  const bool SH = (e == E_NUM);
  const int count = SH ? T_TOK : cnt[e];
  if (mt * 64 >= count) return;
  const int rowbase = SH ? 0 : offs[e];
  const int* tl = toks + e * T_TOK;
  const float* Wb = SH ? Ws : (Wr + (long)e * H_DIM * N2I);
  unsigned short* act = SH ? act_s : act_r;
  const int m0 = mt * 64, n0 = nb * 64;
  __shared__ short As[64 * SKB];
  __shared__ short Bs[2][64 * SKB];
  const int tid = threadIdx.x;
  // A staging: 4 threads/row, 32B each
  const int arow = tid >> 2, ac = (tid & 3) * 16;   // shorts
  const int ar = min(m0 + arow, count - 1);
  const long agrow = SH ? (long)ar : (long)tl[ar];
  const unsigned short* xp = Xb + agrow * H_DIM + ac;
  const int abase = arow * SKB + ac;
  // B staging: per half (128 thr): 16 thr x 4 cols, 8 k-pairs, 4 passes
  const int fm4 = (tid & 15) * 4;
  const int kp  = (tid >> 4) & 7;
  const int hh  = tid >> 7;
  const float* wp0 = Wb + hh * I_DIM + n0 + fm4;
  // MFMA frag ids: 2x2 waves, 32x32 per wave per half
  const int lane = tid & 63, wv = tid >> 6;
  const int wm = (wv >> 1) * 32, wn = (wv & 1) * 32;
  const int fm = lane & 15, fq = lane >> 4;
  f32x4 accg[2][2] = {};
  f32x4 accu[2][2] = {};

  for (int k0 = 0; k0 < H_DIM; k0 += BK) {
    // issue all global loads first (overlap with prior compute + barrier)
    uint4 a0 = *(const uint4*)(xp + k0);
    uint4 a1 = *(const uint4*)(xp + k0 + 8);
    unsigned pb[4][4];
    #pragma unroll
    for (int p2 = 0; p2 < 4; ++p2) {
      const long kr = (long)(k0 + p2 * 16 + kp * 2) * N2I;
      float4 w0 = *(const float4*)(wp0 + kr);
      float4 w1 = *(const float4*)(wp0 + kr + N2I);
      pb[p2][0] = pkbf(w0.x, w1.x);
      pb[p2][1] = pkbf(w0.y, w1.y);
      pb[p2][2] = pkbf(w0.z, w1.z);
      pb[p2][3] = pkbf(w0.w, w1.w);
    }
    __syncthreads();   // prior tile fully consumed
    *(uint4*)&As[abase]     = a0;
    *(uint4*)&As[abase + 8] = a1;
    short* bs = &Bs[hh][0];
    #pragma unroll
    for (int p2 = 0; p2 < 4; ++p2) {
      const int bb = p2 * 16 + kp * 2;
      *(unsigned*)&bs[(fm4 + 0) * SKB + bb] = pb[p2][0];
      *(unsigned*)&bs[(fm4 + 1) * SKB + bb] = pb[p2][1];
      *(unsigned*)&bs[(fm4 + 2) * SKB + bb] = pb[p2][2];
      *(unsigned*)&bs[(fm4 + 3) * SKB + bb] = pb[p2][3];
    }
    __syncthreads();
    #pragma unroll
    for (int kk = 0; kk < 2; ++kk) {
      bf16x8 af[2];
      #pragma unroll
      for (int mi = 0; mi < 2; ++mi) {
        FR f;
        const int ra = (wm + mi * 16 + fm) * SKB + kk * 32 + fq * 8;
        f.d[0] = *(const uint2*)&As[ra];
        f.d[1] = *(const uint2*)&As[ra + 4];
        af[mi] = f.v;
      }
      bf16x8 bg[2], bu[2];
      #pragma unroll
      for (int ni = 0; ni < 2; ++ni) {
        FR f;
        const int rb = (wn + ni * 16 + fm) * SKB + kk * 32 + fq * 8;
        f.d[0] = *(const uint2*)&Bs[0][rb];
        f.d[1] = *(const uint2*)&Bs[0][rb + 4];
        bg[ni] = f.v;
        FR g;
        g.d[0] = *(const uint2*)&Bs[1][rb];
        g.d[1] = *(const uint2*)&Bs[1][rb + 4];
        bu[ni] = g.v;
      }
      #pragma unroll
      for (int mi = 0; mi < 2; ++mi)
        #pragma unroll
        for (int ni = 0; ni < 2; ++ni) {
          accg[mi][ni] = __builtin_amdgcn_mfma_f32_16x16x32_bf16(af[mi], bg[ni], accg[mi][ni], 0, 0, 0);
          accu[mi][ni] = __builtin_amdgcn_mfma_f32_16x16x32_bf16(af[mi], bu[ni], accu[mi][ni], 0, 0, 0);
        }
    }
  }
  // ---- epilogue: act = silu(g) * u, bf16 store ----
  #pragma unroll
  for (int mi = 0; mi < 2; ++mi)
    #pragma unroll
    for (int ni = 0; ni < 2; ++ni)
      #pragma unroll
      for (int r = 0; r < 4; ++r) {
        int lr = wm + mi * 16 + fq * 4 + r;
        int gr = m0 + lr;
        if (gr < count) {
          int lc = wn + ni * 16 + fm;
          float g = accg[mi][ni][r], u = accu[mi][ni][r];
          float a = g / (1.f + __expf(-g)) * u;
          act[(long)(rowbase + gr) * I_DIM + n0 + lc] = (unsigned short)f2bf(a);
        }
      }
}

// ======== down GEMM (merged shared expert as z==E_NUM) ========
// BM=64, BN=64, BK=64, 4 waves (2x2).
__global__ __launch_bounds__(256, 4)
void down_kernel(const unsigned short* __restrict__ act_r, const unsigned short* __restrict__ act_s,
                 const float* __restrict__ Wr, const float* __restrict__ Ws,
                 const int* __restrict__ cnt, const int* __restrict__ offs,
                 const int* __restrict__ toks, const float* __restrict__ tokw,
                 float* __restrict__ eout, float* __restrict__ sout,
                 float* __restrict__ out) {
  const int mt = blockIdx.x, nb = blockIdx.y, e = blockIdx.z;
  const bool SH = (e == E_NUM);
  const int count = SH ? T_TOK : cnt[e];
  if (mt * 64 >= count) return;
  const int rowbase = SH ? 0 : offs[e];
  const unsigned short* ab = SH ? act_s : act_r;
  const float* Wb = SH ? Ws : (Wr + (long)e * I_DIM * H_DIM);
  const int m0 = mt * 64, n0 = nb * 64;
  __shared__ short As[64 * SKB];
  __shared__ short Bs[64 * SKB];
  const int tid = threadIdx.x;
  const int arow = tid >> 2, ac = (tid & 3) * 16;
  const int ar = min(m0 + arow, count - 1);
  const unsigned short* ap = ab + (long)(rowbase + ar) * I_DIM + ac;
  const int abase = arow * SKB + ac;
  const int fm4 = (tid & 15) * 4;
  const int kp  = tid >> 4;            // 0..15 k-pairs within 32-group
  const float* wp0 = Wb + n0 + fm4;
  const int lane = tid & 63, wv = tid >> 6;
  const int wm = (wv >> 1) * 32, wn = (wv & 1) * 32;
  const int fm = lane & 15, fq = lane >> 4;
  f32x4 acc[2][2] = {};

  for (int k0 = 0; k0 < I_DIM; k0 += BK) {
    uint4 a0 = *(const uint4*)(ap + k0);
    uint4 a1 = *(const uint4*)(ap + k0 + 8);
    unsigned pb[2][4];
    #pragma unroll
    for (int p2 = 0; p2 < 2; ++p2) {
      const long kr = (long)(k0 + p2 * 32 + kp * 2) * H_DIM;
      float4 w0 = *(const float4*)(wp0 + kr);
      float4 w1 = *(const float4*)(wp0 + kr + H_DIM);
      pb[p2][0] = pkbf(w0.x, w1.x);
      pb[p2][1] = pkbf(w0.y, w1.y);
      pb[p2][2] = pkbf(w0.z, w1.z);
      pb[p2][3] = pkbf(w0.w, w1.w);
    }
    __syncthreads();
    *(uint4*)&As[abase]     = a0;
    *(uint4*)&As[abase + 8] = a1;
    #pragma unroll
    for (int p2 = 0; p2 < 2; ++p2) {
      const int bb = p2 * 32 + kp * 2;
      *(unsigned*)&Bs[(fm4 + 0) * SKB + bb] = pb[p2][0];
      *(unsigned*)&Bs[(fm4 + 1) * SKB + bb] = pb[p2][1];
      *(unsigned*)&Bs[(fm4 + 2) * SKB + bb] = pb[p2][2];
      *(unsigned*)&Bs[(fm4 + 3) * SKB + bb] = pb[p2][3];
    }
    __syncthreads();
    #pragma unroll
    for (int kk = 0; kk < 2; ++kk) {
      bf16x8 af[2];
      #pragma unroll
      for (int mi = 0; mi < 2; ++mi) {
        FR f;
        const int ra = (wm + mi * 16 + fm) * SKB + kk * 32 + fq * 8;
        f.d[0] = *(const uint2*)&As[ra];
        f.d[1] = *(const uint2*)&As[ra + 4];
        af[mi] = f.v;
      }
      bf16x8 bfr[2];
      #pragma unroll
      for (int ni = 0; ni < 2; ++ni) {
        FR f;
        const int rb = (wn + ni * 16 + fm) * SKB + kk * 32 + fq * 8;
        f.d[0] = *(const uint2*)&Bs[rb];
        f.d[1] = *(const uint2*)&Bs[rb + 4];
        bfr[ni] = f.v;
      }
      #pragma unroll
      for (int mi = 0; mi < 2; ++mi)
        #pragma unroll
        for (int ni = 0; ni < 2; ++ni)
          acc[mi][ni] = __builtin_amdgcn_mfma_f32_16x16x32_bf16(af[mi], bfr[ni], acc[mi][ni], 0, 0, 0);
    }
  }
  #pragma unroll
  for (int mi = 0; mi < 2; ++mi)
    #pragma unroll
    for (int ni = 0; ni < 2; ++ni)
      #pragma unroll
      for (int r = 0; r < 4; ++r) {
        int lr = wm + mi * 16 + fq * 4 + r;
        int gr = m0 + lr;
        if (gr < count) {
          int lc = wn + ni * 16 + fm;
          float v = acc[mi][ni][r];
          if (eout) {
            if (SH) {
              sout[(long)gr * H_DIM + n0 + lc] = v;
            } else {
              float wgt = tokw[e * T_TOK + gr];
              eout[(long)(rowbase + gr) * H_DIM + n0 + lc] = v * wgt;
            }
          } else {
            if (SH) {
              atomicAdd(&out[(long)gr * H_DIM + n0 + lc], v);
            } else {
              float wgt = tokw[e * T_TOK + gr];
              int t = toks[e * T_TOK + gr];
              atomicAdd(&out[(long)t * H_DIM + n0 + lc], v * wgt);
            }
          }
        }
      }
}

// ---------------- combine: out[t] = sout[t] + sum_k eout[slot(t,k)] ----------------
__global__ __launch_bounds__(256)
void combine_kernel(const float* __restrict__ eout, const float* __restrict__ sout,
                    const int* __restrict__ offs, const int* __restrict__ slots,
                    float* __restrict__ out) {
  const int b = blockIdx.x;
  const int t = b >> 1, half = b & 1;
  const int h = half * 1024 + threadIdx.x * 4;
  float4 acc = *(const float4*)(sout + (long)t * H_DIM + h);
  #pragma unroll
  for (int k = 0; k < 8; ++k) {
    int s = slots[t * 8 + k];
    int ei = s >> 10, pos = s & 1023;
    long row = (long)offs[ei] + pos;
    float4 v = *(const float4*)(eout + row * H_DIM + h);
    acc.x += v.x; acc.y += v.y; acc.z += v.z; acc.w += v.w;
  }
  *(float4*)(out + (long)t * H_DIM + h) = acc;
}

// ---------------- launch ----------------
extern "C" void kernel_launch(void* const* d_in, const int* in_sizes, int n_in,
                              void* d_out, int out_size, void* d_ws, size_t ws_size,
                              hipStream_t stream) {
  const float* X   = (const float*)d_in[0];
  const float* GW  = (const float*)d_in[1];
  const float* GB  = (const float*)d_in[2];
  const float* WGU = (const float*)d_in[3];
  const float* WD  = (const float*)d_in[4];
  const float* SGU = (const float*)d_in[5];
  const float* SD  = (const float*)d_in[6];
  float* out = (float*)d_out;
  char* ws = (char*)d_ws;

  int*   cnt   = (int*)(ws + 0);
  int*   offs  = (int*)(ws + 512);
  int*   slots = (int*)(ws + 4096);                         // 32 KB
  int*   toks  = (int*)(ws + 65536);                        // 128 KB
  float* tokw  = (float*)(ws + 196608);                     // 128 KB
  unsigned short* Xb    = (unsigned short*)(ws + 327680);   // 4 MB
  unsigned short* act_s = (unsigned short*)(ws + 4521984);  // 1.5 MB
  unsigned short* act_r = (unsigned short*)(ws + 6094848);  // 12.58 MB
  float* sout = (float*)(ws + 18677760);                    // 8.39 MB
  const size_t EOUT_OFF = 27066368;
  const size_t need = EOUT_OFF + (size_t)8192 * H_DIM * sizeof(float);  // 94.2 MB total
  float* eout = (ws_size >= need) ? (float*)(ws + EOUT_OFF) : nullptr;

  zero_cnt_kernel<<<1, 64, 0, stream>>>(cnt);
  route_kernel<<<T_TOK, 256, 0, stream>>>(X, GW, GB, cnt, toks, tokw, slots);
  offs_kernel<<<1, 64, 0, stream>>>(cnt, offs);
  xconv_kernel<<<T_TOK * H_DIM / 1024, 256, 0, stream>>>(X, Xb);
  // merged shared (z == E_NUM) + routed experts
  gateup_kernel<<<dim3(16, 12, E_NUM + 1), 256, 0, stream>>>(Xb, WGU, SGU, cnt, offs, toks, act_r, act_s);
  if (!eout) hipMemsetAsync(out, 0, (size_t)T_TOK * H_DIM * sizeof(float), stream);
  down_kernel<<<dim3(16, 32, E_NUM + 1), 256, 0, stream>>>(act_r, act_s, WD, SD, cnt, offs, toks, tokw,
                                                           eout, sout, out);
  if (eout) combine_kernel<<<T_TOK * 2, 256, 0, stream>>>(eout, sout, offs, slots, out);
}

// Round 4
// 1170.725 us; speedup vs baseline: 1.3304x; 1.3261x over previous
//
#include <hip/hip_runtime.h>
#include <hip/hip_bf16.h>

#define T_TOK 1024
#define H_DIM 2048
#define E_NUM 32
#define I_DIM 768
#define N2I   1536
#define SKB   72   // fallback path: LDS row stride in shorts (BK=64 + 8 pad)

typedef __attribute__((ext_vector_type(8))) __bf16 bf16x8;
typedef __attribute__((ext_vector_type(4))) float  f32x4;

__device__ __forceinline__ short f2bf(float f) {
  union { float f; unsigned u; } a; a.f = f;
  unsigned u = a.u;
  u += 0x7FFFu + ((u >> 16) & 1u);   // RNE to bf16
  return (short)(u >> 16);
}

// single-instruction packed f32->bf16 (RNE), lo -> D[15:0], hi -> D[31:16]
__device__ __forceinline__ unsigned pkbf(float lo, float hi) {
  unsigned r;
  asm("v_cvt_pk_bf16_f32 %0, %1, %2" : "=v"(r) : "v"(lo), "v"(hi));
  return r;
}

union FR  { uint2 d[2]; bf16x8 v; };
union FRQ { uint4 u;    bf16x8 v; };

// global -> LDS direct DMA, 16B per lane. lds base must be wave-uniform.
__device__ __forceinline__ void gload16(const unsigned short* g, unsigned short* l) {
  __builtin_amdgcn_global_load_lds(
      (const __attribute__((address_space(1))) unsigned int*)g,
      (__attribute__((address_space(3))) unsigned int*)l, 16, 0, 0);
}

// ---------------- routing ----------------
__global__ void zero_cnt_kernel(int* cnt) {
  if (threadIdx.x < E_NUM) cnt[threadIdx.x] = 0;
}

__global__ void route_kernel(const float* __restrict__ X, const float* __restrict__ GW,
                             const float* __restrict__ gbias,
                             int* __restrict__ cnt, int* __restrict__ toks,
                             float* __restrict__ tokw, int* __restrict__ slots) {
  const int t = blockIdx.x;
  const int tid = threadIdx.x;
  __shared__ float xs[H_DIM];
  const float4* xg = (const float4*)(X + (long)t * H_DIM);
  float4* xl = (float4*)xs;
  for (int i = tid; i < H_DIM / 4; i += 256) xl[i] = xg[i];
  __syncthreads();
  const int e = tid >> 3, l = tid & 7;
  const float* w = GW + (long)e * H_DIM;
  float p = 0.f;
  for (int h = l; h < H_DIM; h += 8) p += xs[h] * w[h];
  p += __shfl_xor(p, 4);
  p += __shfl_xor(p, 2);
  p += __shfl_xor(p, 1);
  __shared__ float lg[E_NUM];
  if (l == 0) lg[e] = p;
  __syncthreads();
  if (tid == 0) {
    float su[E_NUM], sc[E_NUM];
    for (int i = 0; i < E_NUM; ++i) {
      float s = 1.f / (1.f + __expf(-lg[i]));
      su[i] = s; sc[i] = s + gbias[i];
    }
    float gs[4];
    for (int g = 0; g < 4; ++g) {
      float m1 = -1e30f, m2 = -1e30f;
      for (int j = 0; j < 8; ++j) {
        float v = sc[g * 8 + j];
        if (v > m1) { m2 = m1; m1 = v; } else if (v > m2) m2 = v;
      }
      gs[g] = m1 + m2;
    }
    int g1 = 0;
    for (int g = 1; g < 4; ++g) if (gs[g] > gs[g1]) g1 = g;
    int g2 = -1;
    for (int g = 0; g < 4; ++g) { if (g == g1) continue; if (g2 < 0 || gs[g] > gs[g2]) g2 = g; }
    bool mask[E_NUM], taken[E_NUM];
    for (int i = 0; i < E_NUM; ++i) {
      int g = i >> 3;
      mask[i] = (g == g1) || (g == g2);
      taken[i] = false;
    }
    int ids[8]; float wsum = 0.f;
    for (int k = 0; k < 8; ++k) {
      int best = -1;
      for (int i = 0; i < E_NUM; ++i) {
        if (!mask[i] || taken[i]) continue;
        if (best < 0 || sc[i] > sc[best]) best = i;
      }
      taken[best] = true; ids[k] = best; wsum += su[best];
    }
    float inv = 2.5f / wsum;
    for (int k = 0; k < 8; ++k) {
      int ei = ids[k];
      int pos = atomicAdd(&cnt[ei], 1);
      toks[ei * T_TOK + pos] = t;
      tokw[ei * T_TOK + pos] = su[ei] * inv;
      slots[t * 8 + k] = (ei << 10) | pos;
    }
  }
}

__global__ void offs_kernel(const int* __restrict__ cnt, int* __restrict__ offs) {
  if (threadIdx.x == 0) {
    int run = 0;
    for (int e = 0; e < E_NUM; ++e) { offs[e] = run; run += cnt[e]; }
    offs[E_NUM] = run;
  }
}

// ---------------- X -> bf16 ----------------
__global__ void xconv_kernel(const float* __restrict__ X, unsigned short* __restrict__ Xb) {
  int i = (blockIdx.x * 256 + threadIdx.x) * 4;
  float4 v = *(const float4*)(X + i);
  uint2 o;
  o.x = pkbf(v.x, v.y);
  o.y = pkbf(v.z, v.w);
  *(uint2*)(Xb + i) = o;
}

// ---------------- weight pre-pass: fp32 [Z][K][N] -> bf16 [Z][N][K] ----------------
__global__ __launch_bounds__(256)
void tr_kernel(const float* __restrict__ in, unsigned short* __restrict__ out,
               int K, int N) {
  const int n0 = blockIdx.x * 32, k0 = blockIdx.y * 64;
  const long z = blockIdx.z;
  const float* ip = in + z * (long)K * N;
  unsigned short* op = out + z * (long)N * K;
  __shared__ float xs[64][36];
  const int tid = threadIdx.x;
  const int kk = tid >> 3, nc = (tid & 7) * 4;
  #pragma unroll
  for (int r = 0; r < 2; ++r) {
    float4 v = *(const float4*)(ip + (long)(k0 + r * 32 + kk) * N + n0 + nc);
    *(float4*)&xs[r * 32 + kk][nc] = v;
  }
  __syncthreads();
  const int n = tid >> 3, kc = (tid & 7) * 8;
  unsigned q0 = pkbf(xs[kc + 0][n], xs[kc + 1][n]);
  unsigned q1 = pkbf(xs[kc + 2][n], xs[kc + 3][n]);
  unsigned q2 = pkbf(xs[kc + 4][n], xs[kc + 5][n]);
  unsigned q3 = pkbf(xs[kc + 6][n], xs[kc + 7][n]);
  *(uint4*)(op + (long)(n0 + n) * K + k0 + kc) = make_uint4(q0, q1, q2, q3);
}

// ======== PRIMARY gate_up + SiLU GEMM: DMA staging from bf16 W^T ========
// BM=64, BN=64 (x2 halves), BK=32, 4 waves (2x2). global_load_lds staging,
// double-buffered LDS, prefetch issued BEFORE compute, XCD-chunked swizzle.
#define GU_NWG (16 * 12 * (E_NUM + 1))   // 6336
#define GU_CPX (GU_NWG / 8)              // 792

__global__ __launch_bounds__(256, 4)
void gateup_dma(const unsigned short* __restrict__ Xb,
                const unsigned short* __restrict__ Wgu_t,  // [E][1536][2048] bf16
                const unsigned short* __restrict__ Sgu_t,  // [1536][2048] bf16
                const int* __restrict__ cnt, const int* __restrict__ offs,
                const int* __restrict__ toks,
                unsigned short* __restrict__ act_r, unsigned short* __restrict__ act_s) {
  const int bid = blockIdx.x;
  const int l = (bid & 7) * GU_CPX + (bid >> 3);   // bijective: 6336 % 8 == 0
  const int mt = l & 15;
  const int panel = l >> 4;
  const int nb = panel % 12;
  const int e  = panel / 12;
  const bool SH = (e == E_NUM);
  const int count = SH ? T_TOK : cnt[e];
  if (mt * 64 >= count) return;
  const int rowbase = SH ? 0 : offs[e];
  const int* tl = toks + e * T_TOK;
  const unsigned short* Wb = SH ? Sgu_t : (Wgu_t + (long)e * N2I * H_DIM);
  unsigned short* act = SH ? act_s : act_r;
  const int m0 = mt * 64, n0 = nb * 64;

  __shared__ __align__(16) unsigned short As[2][64 * 32];
  __shared__ __align__(16) unsigned short Bs[2][2][64 * 32];

  const int tid = threadIdx.x;
  const int lane = tid & 63, wv = tid >> 6;
  // DMA: per wave-instruction, 64 lanes x 16B -> 1024B = 16 LDS rows of 64B.
  const int slot = lane >> 2, gcol = (lane & 3) * 8;
  const int arow = wv * 16 + slot;
  const int ar = min(m0 + arow, count - 1);
  const long atok = SH ? (long)ar : (long)tl[ar];
  const unsigned short* gp_a = Xb + atok * H_DIM + gcol;
  const int bn = n0 + wv * 16 + slot;
  const unsigned short* gp_g = Wb + (long)bn * H_DIM + gcol;
  const unsigned short* gp_u = Wb + (long)(768 + bn) * H_DIM + gcol;
  const int lb = wv * 512;     // wave-uniform LDS segment (shorts)
  // MFMA frag ids
  const int wm = (wv >> 1) * 32, wn = (wv & 1) * 32;
  const int fm = lane & 15, fq = lane >> 4;
  f32x4 accg[2][2] = {}, accu[2][2] = {};

  // prologue: stage tile 0 into buf 0
  gload16(gp_a, &As[0][lb]);
  gload16(gp_g, &Bs[0][0][lb]);
  gload16(gp_u, &Bs[0][1][lb]);
  __syncthreads();

  const int NT = H_DIM / 32;   // 64
  int cur = 0;
  for (int it = 0; it < NT; ++it) {
    if (it + 1 < NT) {
      const int k1 = (it + 1) * 32;
      const int nx = cur ^ 1;
      gload16(gp_a + k1, &As[nx][lb]);
      gload16(gp_g + k1, &Bs[nx][0][lb]);
      gload16(gp_u + k1, &Bs[nx][1][lb]);
    }
    bf16x8 af[2], bg[2], bu[2];
    #pragma unroll
    for (int mi = 0; mi < 2; ++mi) {
      FRQ q; q.u = *(const uint4*)&As[cur][(wm + mi * 16 + fm) * 32 + fq * 8];
      af[mi] = q.v;
    }
    #pragma unroll
    for (int ni = 0; ni < 2; ++ni) {
      FRQ q; q.u = *(const uint4*)&Bs[cur][0][(wn + ni * 16 + fm) * 32 + fq * 8];
      bg[ni] = q.v;
      FRQ r; r.u = *(const uint4*)&Bs[cur][1][(wn + ni * 16 + fm) * 32 + fq * 8];
      bu[ni] = r.v;
    }
    #pragma unroll
    for (int mi = 0; mi < 2; ++mi)
      #pragma unroll
      for (int ni = 0; ni < 2; ++ni) {
        accg[mi][ni] = __builtin_amdgcn_mfma_f32_16x16x32_bf16(af[mi], bg[ni], accg[mi][ni], 0, 0, 0);
        accu[mi][ni] = __builtin_amdgcn_mfma_f32_16x16x32_bf16(af[mi], bu[ni], accu[mi][ni], 0, 0, 0);
      }
    __syncthreads();   // drains prefetch DMA (issued before compute) + joins
    cur ^= 1;
  }
  // epilogue: act = silu(g) * u
  #pragma unroll
  for (int mi = 0; mi < 2; ++mi)
    #pragma unroll
    for (int ni = 0; ni < 2; ++ni)
      #pragma unroll
      for (int r = 0; r < 4; ++r) {
        int lr = wm + mi * 16 + fq * 4 + r;
        int gr = m0 + lr;
        if (gr < count) {
          int lc = wn + ni * 16 + fm;
          float g = accg[mi][ni][r], u = accu[mi][ni][r];
          float a = g / (1.f + __expf(-g)) * u;
          act[(long)(rowbase + gr) * I_DIM + n0 + lc] = (unsigned short)f2bf(a);
        }
      }
}

// ======== PRIMARY down GEMM: DMA staging from bf16 W^T ========
#define DN_NWG (16 * 32 * (E_NUM + 1))   // 16896
#define DN_CPX (DN_NWG / 8)              // 2112

__global__ __launch_bounds__(256, 4)
void down_dma(const unsigned short* __restrict__ act_r, const unsigned short* __restrict__ act_s,
              const unsigned short* __restrict__ Wd_t,   // [E][2048][768] bf16
              const unsigned short* __restrict__ Sd_t,   // [2048][768] bf16
              const int* __restrict__ cnt, const int* __restrict__ offs,
              const float* __restrict__ tokw,
              float* __restrict__ eout, float* __restrict__ sout) {
  const int bid = blockIdx.x;
  const int l = (bid & 7) * DN_CPX + (bid >> 3);
  const int mt = l & 15;
  const int panel = l >> 4;
  const int nb = panel & 31;
  const int e  = panel >> 5;
  const bool SH = (e == E_NUM);
  const int count = SH ? T_TOK : cnt[e];
  if (mt * 64 >= count) return;
  const int rowbase = SH ? 0 : offs[e];
  const unsigned short* ab = SH ? act_s : act_r;
  const unsigned short* Wb = SH ? Sd_t : (Wd_t + (long)e * H_DIM * I_DIM);
  const int m0 = mt * 64, n0 = nb * 64;

  __shared__ __align__(16) unsigned short As[2][64 * 32];
  __shared__ __align__(16) unsigned short Bs[2][64 * 32];

  const int tid = threadIdx.x;
  const int lane = tid & 63, wv = tid >> 6;
  const int slot = lane >> 2, gcol = (lane & 3) * 8;
  const int arow = wv * 16 + slot;
  const int ar = min(m0 + arow, count - 1);
  const unsigned short* gp_a = ab + (long)(rowbase + ar) * I_DIM + gcol;
  const unsigned short* gp_b = Wb + (long)(n0 + wv * 16 + slot) * I_DIM + gcol;
  const int lb = wv * 512;
  const int wm = (wv >> 1) * 32, wn = (wv & 1) * 32;
  const int fm = lane & 15, fq = lane >> 4;
  f32x4 acc[2][2] = {};

  gload16(gp_a, &As[0][lb]);
  gload16(gp_b, &Bs[0][lb]);
  __syncthreads();

  const int NT = I_DIM / 32;   // 24
  int cur = 0;
  for (int it = 0; it < NT; ++it) {
    if (it + 1 < NT) {
      const int k1 = (it + 1) * 32;
      const int nx = cur ^ 1;
      gload16(gp_a + k1, &As[nx][lb]);
      gload16(gp_b + k1, &Bs[nx][lb]);
    }
    bf16x8 af[2], bfr[2];
    #pragma unroll
    for (int mi = 0; mi < 2; ++mi) {
      FRQ q; q.u = *(const uint4*)&As[cur][(wm + mi * 16 + fm) * 32 + fq * 8];
      af[mi] = q.v;
    }
    #pragma unroll
    for (int ni = 0; ni < 2; ++ni) {
      FRQ q; q.u = *(const uint4*)&Bs[cur][(wn + ni * 16 + fm) * 32 + fq * 8];
      bfr[ni] = q.v;
    }
    #pragma unroll
    for (int mi = 0; mi < 2; ++mi)
      #pragma unroll
      for (int ni = 0; ni < 2; ++ni)
        acc[mi][ni] = __builtin_amdgcn_mfma_f32_16x16x32_bf16(af[mi], bfr[ni], acc[mi][ni], 0, 0, 0);
    __syncthreads();
    cur ^= 1;
  }
  #pragma unroll
  for (int mi = 0; mi < 2; ++mi)
    #pragma unroll
    for (int ni = 0; ni < 2; ++ni)
      #pragma unroll
      for (int r = 0; r < 4; ++r) {
        int lr = wm + mi * 16 + fq * 4 + r;
        int gr = m0 + lr;
        if (gr < count) {
          int lc = wn + ni * 16 + fm;
          float v = acc[mi][ni][r];
          if (SH) {
            sout[(long)gr * H_DIM + n0 + lc] = v;
          } else {
            float wgt = tokw[e * T_TOK + gr];
            eout[(long)(rowbase + gr) * H_DIM + n0 + lc] = v * wgt;
          }
        }
      }
}

// ======== FALLBACK GEMMs (round-3 path, used when workspace too small) ========
__global__ __launch_bounds__(256, 4)
void gateup_fb(const unsigned short* __restrict__ Xb,
               const float* __restrict__ Wr, const float* __restrict__ Ws,
               const int* __restrict__ cnt, const int* __restrict__ offs,
               const int* __restrict__ toks,
               unsigned short* __restrict__ act_r, unsigned short* __restrict__ act_s) {
  const int mt = blockIdx.x, nb = blockIdx.y, e = blockIdx.z;
  const bool SH = (e == E_NUM);
  const int count = SH ? T_TOK : cnt[e];
  if (mt * 64 >= count) return;
  const int rowbase = SH ? 0 : offs[e];
  const int* tl = toks + e * T_TOK;
  const float* Wb = SH ? Ws : (Wr + (long)e * H_DIM * N2I);
  unsigned short* act = SH ? act_s : act_r;
  const int m0 = mt * 64, n0 = nb * 64;
  __shared__ short As[64 * SKB];
  __shared__ short Bs[2][64 * SKB];
  const int tid = threadIdx.x;
  const int arow = tid >> 2, ac = (tid & 3) * 16;
  const int ar = min(m0 + arow, count - 1);
  const long agrow = SH ? (long)ar : (long)tl[ar];
  const unsigned short* xp = Xb + agrow * H_DIM + ac;
  const int abase = arow * SKB + ac;
  const int fm4 = (tid & 15) * 4;
  const int kp  = (tid >> 4) & 7;
  const int hh  = tid >> 7;
  const float* wp0 = Wb + hh * I_DIM + n0 + fm4;
  const int lane = tid & 63, wv = tid >> 6;
  const int wm = (wv >> 1) * 32, wn = (wv & 1) * 32;
  const int fm = lane & 15, fq = lane >> 4;
  f32x4 accg[2][2] = {};
  f32x4 accu[2][2] = {};

  for (int k0 = 0; k0 < H_DIM; k0 += 64) {
    uint4 a0 = *(const uint4*)(xp + k0);
    uint4 a1 = *(const uint4*)(xp + k0 + 8);
    unsigned pb[4][4];
    #pragma unroll
    for (int p2 = 0; p2 < 4; ++p2) {
      const long kr = (long)(k0 + p2 * 16 + kp * 2) * N2I;
      float4 w0 = *(const float4*)(wp0 + kr);
      float4 w1 = *(const float4*)(wp0 + kr + N2I);
      pb[p2][0] = pkbf(w0.x, w1.x);
      pb[p2][1] = pkbf(w0.y, w1.y);
      pb[p2][2] = pkbf(w0.z, w1.z);
      pb[p2][3] = pkbf(w0.w, w1.w);
    }
    __syncthreads();
    *(uint4*)&As[abase]     = a0;
    *(uint4*)&As[abase + 8] = a1;
    short* bs = &Bs[hh][0];
    #pragma unroll
    for (int p2 = 0; p2 < 4; ++p2) {
      const int bb = p2 * 16 + kp * 2;
      *(unsigned*)&bs[(fm4 + 0) * SKB + bb] = pb[p2][0];
      *(unsigned*)&bs[(fm4 + 1) * SKB + bb] = pb[p2][1];
      *(unsigned*)&bs[(fm4 + 2) * SKB + bb] = pb[p2][2];
      *(unsigned*)&bs[(fm4 + 3) * SKB + bb] = pb[p2][3];
    }
    __syncthreads();
    #pragma unroll
    for (int kk = 0; kk < 2; ++kk) {
      bf16x8 af[2];
      #pragma unroll
      for (int mi = 0; mi < 2; ++mi) {
        FR f;
        const int ra = (wm + mi * 16 + fm) * SKB + kk * 32 + fq * 8;
        f.d[0] = *(const uint2*)&As[ra];
        f.d[1] = *(const uint2*)&As[ra + 4];
        af[mi] = f.v;
      }
      bf16x8 bg[2], bu[2];
      #pragma unroll
      for (int ni = 0; ni < 2; ++ni) {
        FR f;
        const int rb = (wn + ni * 16 + fm) * SKB + kk * 32 + fq * 8;
        f.d[0] = *(const uint2*)&Bs[0][rb];
        f.d[1] = *(const uint2*)&Bs[0][rb + 4];
        bg[ni] = f.v;
        FR g;
        g.d[0] = *(const uint2*)&Bs[1][rb];
        g.d[1] = *(const uint2*)&Bs[1][rb + 4];
        bu[ni] = g.v;
      }
      #pragma unroll
      for (int mi = 0; mi < 2; ++mi)
        #pragma unroll
        for (int ni = 0; ni < 2; ++ni) {
          accg[mi][ni] = __builtin_amdgcn_mfma_f32_16x16x32_bf16(af[mi], bg[ni], accg[mi][ni], 0, 0, 0);
          accu[mi][ni] = __builtin_amdgcn_mfma_f32_16x16x32_bf16(af[mi], bu[ni], accu[mi][ni], 0, 0, 0);
        }
    }
  }
  #pragma unroll
  for (int mi = 0; mi < 2; ++mi)
    #pragma unroll
    for (int ni = 0; ni < 2; ++ni)
      #pragma unroll
      for (int r = 0; r < 4; ++r) {
        int lr = wm + mi * 16 + fq * 4 + r;
        int gr = m0 + lr;
        if (gr < count) {
          int lc = wn + ni * 16 + fm;
          float g = accg[mi][ni][r], u = accu[mi][ni][r];
          float a = g / (1.f + __expf(-g)) * u;
          act[(long)(rowbase + gr) * I_DIM + n0 + lc] = (unsigned short)f2bf(a);
        }
      }
}

__global__ __launch_bounds__(256, 4)
void down_fb(const unsigned short* __restrict__ act_r, const unsigned short* __restrict__ act_s,
             const float* __restrict__ Wr, const float* __restrict__ Ws,
             const int* __restrict__ cnt, const int* __restrict__ offs,
             const int* __restrict__ toks, const float* __restrict__ tokw,
             float* __restrict__ eout, float* __restrict__ sout,
             float* __restrict__ out) {
  const int mt = blockIdx.x, nb = blockIdx.y, e = blockIdx.z;
  const bool SH = (e == E_NUM);
  const int count = SH ? T_TOK : cnt[e];
  if (mt * 64 >= count) return;
  const int rowbase = SH ? 0 : offs[e];
  const unsigned short* ab = SH ? act_s : act_r;
  const float* Wb = SH ? Ws : (Wr + (long)e * I_DIM * H_DIM);
  const int m0 = mt * 64, n0 = nb * 64;
  __shared__ short As[64 * SKB];
  __shared__ short Bs[64 * SKB];
  const int tid = threadIdx.x;
  const int arow = tid >> 2, ac = (tid & 3) * 16;
  const int ar = min(m0 + arow, count - 1);
  const unsigned short* ap = ab + (long)(rowbase + ar) * I_DIM + ac;
  const int abase = arow * SKB + ac;
  const int fm4 = (tid & 15) * 4;
  const int kp  = tid >> 4;
  const float* wp0 = Wb + n0 + fm4;
  const int lane = tid & 63, wv = tid >> 6;
  const int wm = (wv >> 1) * 32, wn = (wv & 1) * 32;
  const int fm = lane & 15, fq = lane >> 4;
  f32x4 acc[2][2] = {};

  for (int k0 = 0; k0 < I_DIM; k0 += 64) {
    uint4 a0 = *(const uint4*)(ap + k0);
    uint4 a1 = *(const uint4*)(ap + k0 + 8);
    unsigned pb[2][4];
    #pragma unroll
    for (int p2 = 0; p2 < 2; ++p2) {
      const long kr = (long)(k0 + p2 * 32 + kp * 2) * H_DIM;
      float4 w0 = *(const float4*)(wp0 + kr);
      float4 w1 = *(const float4*)(wp0 + kr + H_DIM);
      pb[p2][0] = pkbf(w0.x, w1.x);
      pb[p2][1] = pkbf(w0.y, w1.y);
      pb[p2][2] = pkbf(w0.z, w1.z);
      pb[p2][3] = pkbf(w0.w, w1.w);
    }
    __syncthreads();
    *(uint4*)&As[abase]     = a0;
    *(uint4*)&As[abase + 8] = a1;
    #pragma unroll
    for (int p2 = 0; p2 < 2; ++p2) {
      const int bb = p2 * 32 + kp * 2;
      *(unsigned*)&Bs[(fm4 + 0) * SKB + bb] = pb[p2][0];
      *(unsigned*)&Bs[(fm4 + 1) * SKB + bb] = pb[p2][1];
      *(unsigned*)&Bs[(fm4 + 2) * SKB + bb] = pb[p2][2];
      *(unsigned*)&Bs[(fm4 + 3) * SKB + bb] = pb[p2][3];
    }
    __syncthreads();
    #pragma unroll
    for (int kk = 0; kk < 2; ++kk) {
      bf16x8 af[2];
      #pragma unroll
      for (int mi = 0; mi < 2; ++mi) {
        FR f;
        const int ra = (wm + mi * 16 + fm) * SKB + kk * 32 + fq * 8;
        f.d[0] = *(const uint2*)&As[ra];
        f.d[1] = *(const uint2*)&As[ra + 4];
        af[mi] = f.v;
      }
      bf16x8 bfr[2];
      #pragma unroll
      for (int ni = 0; ni < 2; ++ni) {
        FR f;
        const int rb = (wn + ni * 16 + fm) * SKB + kk * 32 + fq * 8;
        f.d[0] = *(const uint2*)&Bs[rb];
        f.d[1] = *(const uint2*)&Bs[rb + 4];
        bfr[ni] = f.v;
      }
      #pragma unroll
      for (int mi = 0; mi < 2; ++mi)
        #pragma unroll
        for (int ni = 0; ni < 2; ++ni)
          acc[mi][ni] = __builtin_amdgcn_mfma_f32_16x16x32_bf16(af[mi], bfr[ni], acc[mi][ni], 0, 0, 0);
    }
  }
  #pragma unroll
  for (int mi = 0; mi < 2; ++mi)
    #pragma unroll
    for (int ni = 0; ni < 2; ++ni)
      #pragma unroll
      for (int r = 0; r < 4; ++r) {
        int lr = wm + mi * 16 + fq * 4 + r;
        int gr = m0 + lr;
        if (gr < count) {
          int lc = wn + ni * 16 + fm;
          float v = acc[mi][ni][r];
          if (eout) {
            if (SH) {
              sout[(long)gr * H_DIM + n0 + lc] = v;
            } else {
              float wgt = tokw[e * T_TOK + gr];
              eout[(long)(rowbase + gr) * H_DIM + n0 + lc] = v * wgt;
            }
          } else {
            if (SH) {
              atomicAdd(&out[(long)gr * H_DIM + n0 + lc], v);
            } else {
              float wgt = tokw[e * T_TOK + gr];
              int t = toks[e * T_TOK + gr];
              atomicAdd(&out[(long)t * H_DIM + n0 + lc], v * wgt);
            }
          }
        }
      }
}

// ---------------- combine: out[t] = sout[t] + sum_k eout[slot(t,k)] ----------------
__global__ __launch_bounds__(256)
void combine_kernel(const float* __restrict__ eout, const float* __restrict__ sout,
                    const int* __restrict__ offs, const int* __restrict__ slots,
                    float* __restrict__ out) {
  const int b = blockIdx.x;
  const int t = b >> 1, half = b & 1;
  const int h = half * 1024 + threadIdx.x * 4;
  float4 acc = *(const float4*)(sout + (long)t * H_DIM + h);
  #pragma unroll
  for (int k = 0; k < 8; ++k) {
    int s = slots[t * 8 + k];
    int ei = s >> 10, pos = s & 1023;
    long row = (long)offs[ei] + pos;
    float4 v = *(const float4*)(eout + row * H_DIM + h);
    acc.x += v.x; acc.y += v.y; acc.z += v.z; acc.w += v.w;
  }
  *(float4*)(out + (long)t * H_DIM + h) = acc;
}

// ---------------- launch ----------------
extern "C" void kernel_launch(void* const* d_in, const int* in_sizes, int n_in,
                              void* d_out, int out_size, void* d_ws, size_t ws_size,
                              hipStream_t stream) {
  const float* X   = (const float*)d_in[0];
  const float* GW  = (const float*)d_in[1];
  const float* GB  = (const float*)d_in[2];
  const float* WGU = (const float*)d_in[3];
  const float* WD  = (const float*)d_in[4];
  const float* SGU = (const float*)d_in[5];
  const float* SD  = (const float*)d_in[6];
  float* out = (float*)d_out;
  char* ws = (char*)d_ws;

  int*   cnt   = (int*)(ws + 0);
  int*   offs  = (int*)(ws + 512);
  int*   slots = (int*)(ws + 4096);                         // 32 KB
  int*   toks  = (int*)(ws + 65536);                        // 128 KB
  float* tokw  = (float*)(ws + 196608);                     // 128 KB
  unsigned short* Xb    = (unsigned short*)(ws + 327680);   // 4 MB
  unsigned short* act_s = (unsigned short*)(ws + 4521984);  // 1.5 MB
  unsigned short* act_r = (unsigned short*)(ws + 6094848);  // 12.58 MB
  float* sout = (float*)(ws + 18677760);                    // 8.39 MB
  const size_t EOUT_OFF = 27066368UL;
  const size_t FB_NEED  = EOUT_OFF + (size_t)8192 * H_DIM * sizeof(float);  // 94,175,232
  float* eout = (ws_size >= FB_NEED) ? (float*)(ws + EOUT_OFF) : nullptr;

  const size_t WGU_T_OFF = 94175232UL;
  const size_t WD_T_OFF  = WGU_T_OFF + (size_t)E_NUM * N2I * H_DIM * 2;   // +201.3 MB
  const size_t SGU_T_OFF = WD_T_OFF  + (size_t)E_NUM * H_DIM * I_DIM * 2; // +100.7 MB
  const size_t SD_T_OFF  = SGU_T_OFF + (size_t)N2I * H_DIM * 2;           // +6.3 MB
  const size_t PRI_NEED  = SD_T_OFF  + (size_t)H_DIM * I_DIM * 2;         // ~405.6 MB
  unsigned short* Wgu_t = (unsigned short*)(ws + WGU_T_OFF);
  unsigned short* Wd_t  = (unsigned short*)(ws + WD_T_OFF);
  unsigned short* Sgu_t = (unsigned short*)(ws + SGU_T_OFF);
  unsigned short* Sd_t  = (unsigned short*)(ws + SD_T_OFF);

  zero_cnt_kernel<<<1, 64, 0, stream>>>(cnt);
  route_kernel<<<T_TOK, 256, 0, stream>>>(X, GW, GB, cnt, toks, tokw, slots);
  offs_kernel<<<1, 64, 0, stream>>>(cnt, offs);
  xconv_kernel<<<T_TOK * H_DIM / 1024, 256, 0, stream>>>(X, Xb);

  if (ws_size >= PRI_NEED) {
    // weight pre-pass: fp32 [Z][K][N] -> bf16 [Z][N][K]
    tr_kernel<<<dim3(N2I / 32, H_DIM / 64, E_NUM), 256, 0, stream>>>(WGU, Wgu_t, H_DIM, N2I);
    tr_kernel<<<dim3(H_DIM / 32, I_DIM / 64, E_NUM), 256, 0, stream>>>(WD, Wd_t, I_DIM, H_DIM);
    tr_kernel<<<dim3(N2I / 32, H_DIM / 64, 1), 256, 0, stream>>>(SGU, Sgu_t, H_DIM, N2I);
    tr_kernel<<<dim3(H_DIM / 32, I_DIM / 64, 1), 256, 0, stream>>>(SD, Sd_t, I_DIM, H_DIM);
    gateup_dma<<<GU_NWG, 256, 0, stream>>>(Xb, Wgu_t, Sgu_t, cnt, offs, toks, act_r, act_s);
    down_dma<<<DN_NWG, 256, 0, stream>>>(act_r, act_s, Wd_t, Sd_t, cnt, offs, tokw, eout, sout);
    combine_kernel<<<T_TOK * 2, 256, 0, stream>>>(eout, sout, offs, slots, out);
  } else {
    gateup_fb<<<dim3(16, 12, E_NUM + 1), 256, 0, stream>>>(Xb, WGU, SGU, cnt, offs, toks, act_r, act_s);
    if (!eout) hipMemsetAsync(out, 0, (size_t)T_TOK * H_DIM * sizeof(float), stream);
    down_fb<<<dim3(16, 32, E_NUM + 1), 256, 0, stream>>>(act_r, act_s, WD, SD, cnt, offs, toks, tokw,
                                                         eout, sout, out);
    if (eout) combine_kernel<<<T_TOK * 2, 256, 0, stream>>>(eout, sout, offs, slots, out);
  }
}